// Round 4
// baseline (2336.634 us; speedup 1.0000x reference)
//
#include <hip/hip_runtime.h>
#include <hip/hip_bf16.h>

// ---------- helpers ----------
__device__ __forceinline__ float bf2f(unsigned short u) {
    union { unsigned int i; float f; } x; x.i = ((unsigned int)u) << 16; return x.f;
}
__device__ __forceinline__ unsigned short f2bf(float f) {
    union { float f; unsigned int i; } x; x.f = f;
    unsigned int r = x.i + 0x7fffu + ((x.i >> 16) & 1u);   // RTNE
    return (unsigned short)(r >> 16);
}
__device__ __forceinline__ float sigm(float x) { return 1.0f / (1.0f + __expf(-x)); }
__device__ __forceinline__ float ftanh(float x) {
    x = fminf(15.f, fmaxf(-15.f, x));
    float t = __expf(2.0f * x);
    return (t - 1.0f) / (t + 1.0f);
}

typedef __attribute__((ext_vector_type(8))) short bf16x8;
typedef __attribute__((ext_vector_type(4))) float f32x4;

__device__ __forceinline__ bf16x8 pack8(float4 a, float4 b) {
    bf16x8 v;
    v[0] = (short)f2bf(a.x); v[1] = (short)f2bf(a.y);
    v[2] = (short)f2bf(a.z); v[3] = (short)f2bf(a.w);
    v[4] = (short)f2bf(b.x); v[5] = (short)f2bf(b.y);
    v[6] = (short)f2bf(b.z); v[7] = (short)f2bf(b.w);
    return v;
}

// ---------- fp32 -> bf16 convert (8 elems/thread) ----------
__global__ __launch_bounds__(256) void cvt_f32_bf16(
    const float* __restrict__ in, unsigned short* __restrict__ out, int n8)
{
    int i = blockIdx.x * 256 + threadIdx.x;
    if (i >= n8) return;
    float4 a = *(const float4*)(in + (size_t)i * 8);
    float4 b = *(const float4*)(in + (size_t)i * 8 + 4);
    *(bf16x8*)(out + (size_t)i * 8) = pack8(a, b);
}

// ---------- x [b][t][128] fp32 -> xb [t*512+b][128] bf16 ----------
__global__ __launch_bounds__(256) void cvt_x_transpose(
    const float* __restrict__ in, unsigned short* __restrict__ out)
{
    int c = blockIdx.x * 256 + threadIdx.x;      // 1,048,576 chunks of 8
    int b = c >> 11, t = (c >> 4) & 127, kc = c & 15;
    const float* src = in + (((size_t)b * 128 + t) * 16 + kc) * 8;
    float4 a = *(const float4*)src;
    float4 bb = *(const float4*)(src + 4);
    *(bf16x8*)(out + (((size_t)t * 512 + b) * 16 + kc) * 8) = pack8(a, bb);
}

// ---------- MFMA GEMM: C[m][n] = A[m,:]·B[n,:] + bias, bf16 inputs ----------
// 128x128 tile, BK=64, 256 threads = 4 waves (2x2), 64x64 out per wave.
// PERM: store col n at sigma(n) = (n&~31)|((n&15)<<1)|((n>>4)&1)  (cg-interleave)
template<int K, bool OUT_BF16, bool GUARD_N, bool PERM>
__global__ __launch_bounds__(256) void gemm_mfma(
    const unsigned short* __restrict__ A,    // [M][K] bf16
    const unsigned short* __restrict__ Bm,   // [N][K] bf16
    const float* __restrict__ bias0,
    const float* __restrict__ bias1,         // may be null
    void* __restrict__ Cptr, long ldC, int N)
{
    constexpr int LDA = 72;                   // 64 + 8 pad (row = 144 B = 9*16)
    __shared__ unsigned short As[128 * LDA];
    __shared__ unsigned short Bs[128 * LDA];
    const int tid = threadIdx.x;
    const int lane = tid & 63;
    const int l15 = lane & 15, lg = lane >> 4;
    const int wid = tid >> 6;
    const int wr = wid >> 1, wc = wid & 1;
    const int m0 = blockIdx.y * 128, n0 = blockIdx.x * 128;
    const int srow = tid >> 3;                // 0..31
    const int scol = (tid & 7) * 8;           // 0..56

    f32x4 acc[4][4];
    #pragma unroll
    for (int mi = 0; mi < 4; ++mi)
        #pragma unroll
        for (int ni = 0; ni < 4; ++ni)
            acc[mi][ni] = (f32x4){0.f, 0.f, 0.f, 0.f};

    for (int kt = 0; kt < K / 64; ++kt) {
        bf16x8 avals[4], bvals[4];
        #pragma unroll
        for (int i = 0; i < 4; ++i) {
            avals[i] = *(const bf16x8*)(A + (size_t)(m0 + i * 32 + srow) * K + kt * 64 + scol);
            int brow = n0 + i * 32 + srow;
            if (GUARD_N) brow = (brow < N) ? brow : (N - 1);
            bvals[i] = *(const bf16x8*)(Bm + (size_t)brow * K + kt * 64 + scol);
        }
        __syncthreads();   // previous iter's reads complete
        #pragma unroll
        for (int i = 0; i < 4; ++i) {
            *(bf16x8*)&As[(i * 32 + srow) * LDA + scol] = avals[i];
            *(bf16x8*)&Bs[(i * 32 + srow) * LDA + scol] = bvals[i];
        }
        __syncthreads();
        #pragma unroll
        for (int ks = 0; ks < 2; ++ks) {
            bf16x8 af[4], bf[4];
            #pragma unroll
            for (int mi = 0; mi < 4; ++mi)
                af[mi] = *(const bf16x8*)&As[(wr * 64 + mi * 16 + l15) * LDA + ks * 32 + lg * 8];
            #pragma unroll
            for (int ni = 0; ni < 4; ++ni)
                bf[ni] = *(const bf16x8*)&Bs[(wc * 64 + ni * 16 + l15) * LDA + ks * 32 + lg * 8];
            #pragma unroll
            for (int mi = 0; mi < 4; ++mi)
                #pragma unroll
                for (int ni = 0; ni < 4; ++ni)
                    acc[mi][ni] = __builtin_amdgcn_mfma_f32_16x16x32_bf16(
                        af[mi], bf[ni], acc[mi][ni], 0, 0, 0);
        }
    }

    #pragma unroll
    for (int ni = 0; ni < 4; ++ni) {
        int n = n0 + wc * 64 + ni * 16 + l15;
        bool nok = (!GUARD_N) || (n < N);
        float bsum = 0.f;
        if (nok) { bsum = bias0[n]; if (bias1) bsum += bias1[n]; }
        int ns = PERM ? ((n & ~31) | ((n & 15) << 1) | ((n >> 4) & 1)) : n;
        #pragma unroll
        for (int mi = 0; mi < 4; ++mi) {
            int m = m0 + wr * 64 + mi * 16 + lg * 4;
            #pragma unroll
            for (int r = 0; r < 4; ++r) {
                float v = acc[mi][ni][r] + bsum;
                if (nok) {
                    if (OUT_BF16)
                        ((unsigned short*)Cptr)[(size_t)(m + r) * ldC + ns] = f2bf(v);
                    else
                        ((float*)Cptr)[(size_t)(m + r) * ldC + ns] = v;
                }
            }
        }
    }
}

// ---------- persistent LSTM layer ----------
#define RFRAGS 46
#define LFRAGS 18
#define LDS_HBYTES 8448            // 16*264*2
#define LDS_TOTAL (LDS_HBYTES + LFRAGS * 8 * 1024)   // 155904

__device__ __forceinline__ void lstm_step_body(
    int t, const unsigned short* __restrict__ G, size_t gbase,
    unsigned int* __restrict__ cur, unsigned int* __restrict__ nxt,
    char* __restrict__ smem, char* __restrict__ ldsW,
    const bf16x8* __restrict__ wreg, float (*__restrict__ cst)[4],
    int w, int l, int l15, int lg, int bc,
    unsigned short* __restrict__ h0out, unsigned short* __restrict__ hlast)
{
    // ---- prefetch G(t+1): 16 packed u32 loads, stay in flight across barriers ----
    const unsigned short* Gn = G + ((size_t)(t + 1) * 512 * 1024) + gbase;
    #pragma unroll
    for (int ty = 0; ty < 4; ++ty)
        #pragma unroll
        for (int r = 0; r < 4; ++r)
            nxt[ty * 4 + r] = *(const unsigned int*)(Gn + ty * 256 + (size_t)r * 1024);

    unsigned short hb16[2][4];
    #pragma unroll
    for (int cg = 0; cg < 2; ++cg) {
        f32x4 acc[4];
        #pragma unroll
        for (int ty = 0; ty < 4; ++ty) acc[ty] = (f32x4){0.f, 0.f, 0.f, 0.f};

        #pragma unroll
        for (int ks = 0; ks < 8; ++ks) {
            bf16x8 a = *(const bf16x8*)(smem + l15 * 528 + ks * 64 + lg * 16);
            #pragma unroll
            for (int ty = 0; ty < 4; ++ty) {
                const int f = cg * 32 + ty * 8 + ks;
                bf16x8 b;
                if (f < RFRAGS) b = wreg[f];
                else b = *(const bf16x8*)(ldsW + (w * LFRAGS + (f - RFRAGS)) * 1024 + l * 16);
                acc[ty] = __builtin_amdgcn_mfma_f32_16x16x32_bf16(a, b, acc[ty], 0, 0, 0);
            }
        }

        #pragma unroll
        for (int r = 0; r < 4; ++r) {
            float pre[4];
            #pragma unroll
            for (int ty = 0; ty < 4; ++ty) {
                unsigned int p = cur[ty * 4 + r];
                unsigned short g16 = (cg == 0) ? (unsigned short)(p & 0xffffu)
                                               : (unsigned short)(p >> 16);
                pre[ty] = acc[ty][r] + bf2f(g16);
            }
            float ii = sigm(pre[0]), ff = sigm(pre[1]);
            float gg = ftanh(pre[2]), oo = sigm(pre[3]);
            float cn = ff * cst[cg][r] + ii * gg;
            cst[cg][r] = cn;
            float hn = oo * ftanh(cn);
            hb16[cg][r] = f2bf(hn);
            if (h0out)
                h0out[((size_t)t * 512 + bc * 16 + lg * 4 + r) * 256
                      + w * 32 + cg * 16 + l15] = hb16[cg][r];
            if (hlast && t == 127)
                hlast[(size_t)(bc * 16 + lg * 4 + r) * 256
                      + w * 32 + cg * 16 + l15] = hb16[cg][r];
        }
    }

    // barrier 1: all waves done reading h(t-1). Drain DS only; leave vmcnt alone.
    asm volatile("s_waitcnt lgkmcnt(0)" ::: "memory");
    __builtin_amdgcn_s_barrier();

    #pragma unroll
    for (int cg = 0; cg < 2; ++cg)
        #pragma unroll
        for (int r = 0; r < 4; ++r)
            *(unsigned short*)(smem + (lg * 4 + r) * 528
                               + (w * 32 + cg * 16 + l15) * 2) = hb16[cg][r];

    // barrier 2: h(t) visible.
    asm volatile("s_waitcnt lgkmcnt(0)" ::: "memory");
    __builtin_amdgcn_s_barrier();
}

__global__ __launch_bounds__(512, 2) void lstm_persist(
    const unsigned short* __restrict__ G,    // [128][512][1024] bf16, cg-interleaved cols
    const float* __restrict__ Whh,           // [1024][256] f32
    unsigned short* __restrict__ h0out,      // layer0: [t*512+b][256] bf16, else nullptr
    unsigned short* __restrict__ hlast)      // layer1: [512][256] bf16 at t=127, else nullptr
{
    extern __shared__ char smem[];
    char* ldsW = smem + LDS_HBYTES;

    const int lid = threadIdx.x;
    const int w = lid >> 6;
    const int l = lid & 63;
    const int l15 = l & 15, lg = l >> 4;
    const int bc = blockIdx.x;

    bf16x8 wreg[RFRAGS];
    #pragma unroll
    for (int f = 0; f < RFRAGS; ++f) {
        const int cg = f >> 5, type = (f >> 3) & 3, ks = f & 7;
        const int grow = type * 256 + w * 32 + cg * 16 + l15;
        const int k0 = ks * 32 + lg * 8;
        const float* src = Whh + (size_t)grow * 256 + k0;
        wreg[f] = pack8(*(const float4*)src, *(const float4*)(src + 4));
    }
    for (int f = RFRAGS; f < 64; ++f) {
        const int cg = f >> 5, type = (f >> 3) & 3, ks = f & 7;
        const int grow = type * 256 + w * 32 + cg * 16 + l15;
        const int k0 = ks * 32 + lg * 8;
        const float* src = Whh + (size_t)grow * 256 + k0;
        *(bf16x8*)(ldsW + (size_t)(w * LFRAGS + (f - RFRAGS)) * 1024 + l * 16) =
            pack8(*(const float4*)src, *(const float4*)(src + 4));
    }

    for (int i = lid; i < 16 * 264; i += 512) ((unsigned short*)smem)[i] = 0;
    __syncthreads();

    float cst[2][4] = {};
    unsigned int gvA[16], gvB[16];

    // gbase: this thread's packed-u32 G offset (element units), excluding t term
    const size_t gbase = (size_t)bc * 16 * 1024 + (size_t)lg * 4 * 1024
                       + w * 32 + l15 * 2;

    // prologue: load t=0 gate values
    {
        const unsigned short* G0 = G + gbase;
        #pragma unroll
        for (int ty = 0; ty < 4; ++ty)
            #pragma unroll
            for (int r = 0; r < 4; ++r)
                gvA[ty * 4 + r] = *(const unsigned int*)(G0 + ty * 256 + (size_t)r * 1024);
    }

    for (int t = 0; t < 128; t += 2) {
        lstm_step_body(t,     G, gbase, gvA, gvB, smem, ldsW, wreg, cst,
                       w, l, l15, lg, bc, h0out, hlast);
        lstm_step_body(t + 1, G, gbase, gvB, gvA, smem, ldsW, wreg, cst,
                       w, l, l15, lg, bc, h0out, hlast);
    }
}

// ---------- row softmax over 50257 ----------
__global__ __launch_bounds__(256) void softmax_rows(
    const float* __restrict__ logits, float* __restrict__ out)
{
    const int b = blockIdx.x;
    const int lid = threadIdx.x;
    const float* row = logits + (size_t)b * 50257;
    __shared__ float red[256];

    float m = -3.4e38f;
    for (int v = lid; v < 50257; v += 256) m = fmaxf(m, row[v]);
    red[lid] = m; __syncthreads();
    for (int s = 128; s > 0; s >>= 1) {
        if (lid < s) red[lid] = fmaxf(red[lid], red[lid + s]);
        __syncthreads();
    }
    m = red[0]; __syncthreads();

    float sum = 0.f;
    for (int v = lid; v < 50257; v += 256) sum += __expf(row[v] - m);
    red[lid] = sum; __syncthreads();
    for (int s = 128; s > 0; s >>= 1) {
        if (lid < s) red[lid] += red[lid + s];
        __syncthreads();
    }
    float inv = 1.0f / red[0];

    float* orow = out + (size_t)b * 50257;
    for (int v = lid; v < 50257; v += 256) orow[v] = __expf(row[v] - m) * inv;
}

// ---------- host ----------
extern "C" void kernel_launch(void* const* d_in, const int* in_sizes, int n_in,
                              void* d_out, int out_size, void* d_ws, size_t ws_size,
                              hipStream_t stream) {
    (void)in_sizes; (void)n_in; (void)out_size; (void)ws_size;
    const float* x    = (const float*)d_in[0];
    const float* Wih0 = (const float*)d_in[1];
    const float* Whh0 = (const float*)d_in[2];
    const float* bih0 = (const float*)d_in[3];
    const float* bhh0 = (const float*)d_in[4];
    const float* Wih1 = (const float*)d_in[5];
    const float* Whh1 = (const float*)d_in[6];
    const float* bih1 = (const float*)d_in[7];
    const float* bhh1 = (const float*)d_in[8];
    const float* fcW  = (const float*)d_in[9];
    const float* fcb  = (const float*)d_in[10];
    float* out = (float*)d_out;

    char* ws = (char*)d_ws;
    unsigned short* G      = (unsigned short*)ws;                 // 134,217,728 B
    unsigned short* h0all  = (unsigned short*)(ws + 134217728);   // 33,554,432 B
    unsigned short* xb     = h0all;                               // alias: dead before lstm0 writes h0all
    char* misc             = ws + 167772160;
    unsigned short* W0b    = (unsigned short*)(misc);             // 262,144 B
    unsigned short* W1b    = (unsigned short*)(misc + 262144);    // 524,288 B
    unsigned short* hlastb = (unsigned short*)(misc + 786432);    // 262,144 B
    float* logits          = (float*)ws;                          // 102,926,336 B (reuses G)
    unsigned short* fcWb   = (unsigned short*)(ws + 103809024);   // 25,731,584 B (in G region, past logits)

    static bool attr_set = false;
    if (!attr_set) {
        hipFuncSetAttribute((const void*)lstm_persist,
                            hipFuncAttributeMaxDynamicSharedMemorySize, LDS_TOTAL);
        attr_set = true;
    }

    // ----- layer 0 -----
    cvt_x_transpose<<<4096, 256, 0, stream>>>(x, xb);
    cvt_f32_bf16<<<64, 256, 0, stream>>>(Wih0, W0b, 16384);
    gemm_mfma<128, true, false, true><<<dim3(8, 512), 256, 0, stream>>>(
        xb, W0b, bih0, bhh0, G, 1024, 1024);
    lstm_persist<<<32, 512, LDS_TOTAL, stream>>>(G, Whh0, h0all, nullptr);
    // ----- layer 1 -----
    cvt_f32_bf16<<<128, 256, 0, stream>>>(Wih1, W1b, 32768);
    gemm_mfma<256, true, false, true><<<dim3(8, 512), 256, 0, stream>>>(
        h0all, W1b, bih1, bhh1, G, 1024, 1024);
    lstm_persist<<<32, 512, LDS_TOTAL, stream>>>(G, Whh1, nullptr, hlastb);
    // ----- FC + softmax -----
    cvt_f32_bf16<<<6283, 256, 0, stream>>>(fcW, fcWb, 1608224);
    gemm_mfma<256, false, true, false><<<dim3(393, 4), 256, 0, stream>>>(
        hlastb, fcWb, fcb, nullptr, logits, 50257, 50257);
    softmax_rows<<<512, 256, 0, stream>>>(logits, out);
}

// Round 5
// 1841.112 us; speedup vs baseline: 1.2691x; 1.2691x over previous
//
#include <hip/hip_runtime.h>
#include <hip/hip_bf16.h>

// ---------- helpers ----------
__device__ __forceinline__ float bf2f(unsigned short u) {
    union { unsigned int i; float f; } x; x.i = ((unsigned int)u) << 16; return x.f;
}
__device__ __forceinline__ unsigned short f2bf(float f) {
    union { float f; unsigned int i; } x; x.f = f;
    unsigned int r = x.i + 0x7fffu + ((x.i >> 16) & 1u);   // RTNE
    return (unsigned short)(r >> 16);
}
__device__ __forceinline__ float sigm(float x) { return 1.0f / (1.0f + __expf(-x)); }
__device__ __forceinline__ float ftanh(float x) {
    x = fminf(15.f, fmaxf(-15.f, x));
    float t = __expf(2.0f * x);
    return (t - 1.0f) / (t + 1.0f);
}

typedef __attribute__((ext_vector_type(8))) short bf16x8;
typedef __attribute__((ext_vector_type(4))) float f32x4;

__device__ __forceinline__ bf16x8 pack8(float4 a, float4 b) {
    bf16x8 v;
    v[0] = (short)f2bf(a.x); v[1] = (short)f2bf(a.y);
    v[2] = (short)f2bf(a.z); v[3] = (short)f2bf(a.w);
    v[4] = (short)f2bf(b.x); v[5] = (short)f2bf(b.y);
    v[6] = (short)f2bf(b.z); v[7] = (short)f2bf(b.w);
    return v;
}

// ---------- fp32 -> bf16 convert (8 elems/thread) ----------
__global__ __launch_bounds__(256) void cvt_f32_bf16(
    const float* __restrict__ in, unsigned short* __restrict__ out, int n8)
{
    int i = blockIdx.x * 256 + threadIdx.x;
    if (i >= n8) return;
    float4 a = *(const float4*)(in + (size_t)i * 8);
    float4 b = *(const float4*)(in + (size_t)i * 8 + 4);
    *(bf16x8*)(out + (size_t)i * 8) = pack8(a, b);
}

// ---------- x [b][t][128] fp32 -> xb [t*512+b][128] bf16 ----------
__global__ __launch_bounds__(256) void cvt_x_transpose(
    const float* __restrict__ in, unsigned short* __restrict__ out)
{
    int c = blockIdx.x * 256 + threadIdx.x;      // 1,048,576 chunks of 8
    int b = c >> 11, t = (c >> 4) & 127, kc = c & 15;
    const float* src = in + (((size_t)b * 128 + t) * 16 + kc) * 8;
    float4 a = *(const float4*)src;
    float4 bb = *(const float4*)(src + 4);
    *(bf16x8*)(out + (((size_t)t * 512 + b) * 16 + kc) * 8) = pack8(a, bb);
}

// ---------- weight partition for lstm_persist ----------
// 64 frags/wave: f -> (cg=f>>5, type=(f>>3)&3, ks=f&7)
//   f in [0,28)  : registers (AGPR-able)
//   f in [28,47) : LDS resident
//   f in [47,64) : streamed each step from pre-packed Wstr
#define RFRAGS 28
#define LFRAGS 19
#define SFRAGS 17
#define LDS_HB 8192                                 // h: 16 rows x 512 B, XOR-swizzled
#define LDS_TOTAL (LDS_HB + LFRAGS * 8 * 1024)      // 163840 = 160 KiB exactly

// pack streamed frags: Wstr[((w*17+sf)*64 + l)*8 .. +8) = Whh[grow][k0..k0+8)
__global__ __launch_bounds__(256) void pack_stream(
    const float* __restrict__ Whh, unsigned short* __restrict__ Wstr)
{
    int gid = blockIdx.x * 256 + threadIdx.x;
    if (gid >= 8 * SFRAGS * 64) return;
    int l = gid & 63, sf = (gid >> 6) % SFRAGS, w = gid / (SFRAGS * 64);
    int f = 47 + sf;
    int cg = f >> 5, ty = (f >> 3) & 3, ks = f & 7;
    int l15 = l & 15, lg = l >> 4;
    int grow = ty * 256 + w * 32 + cg * 16 + l15;
    int k0 = ks * 32 + lg * 8;
    const float* src = Whh + (size_t)grow * 256 + k0;
    *(bf16x8*)(Wstr + (size_t)gid * 8) = pack8(*(const float4*)src, *(const float4*)(src + 4));
}

// ---------- MFMA GEMM: C[m][n] = A[m,:]·B[n,:] + bias, bf16 inputs ----------
// PERM: store col n at sigma(n) = (n&~31)|((n&15)<<1)|((n>>4)&1)  (cg-interleave)
template<int K, bool OUT_BF16, bool GUARD_N, bool PERM>
__global__ __launch_bounds__(256) void gemm_mfma(
    const unsigned short* __restrict__ A,    // [M][K] bf16
    const unsigned short* __restrict__ Bm,   // [N][K] bf16
    const float* __restrict__ bias0,
    const float* __restrict__ bias1,         // may be null
    void* __restrict__ Cptr, long ldC, int N)
{
    constexpr int LDA = 72;                   // 64 + 8 pad (row = 144 B = 9*16)
    __shared__ unsigned short As[128 * LDA];
    __shared__ unsigned short Bs[128 * LDA];
    const int tid = threadIdx.x;
    const int lane = tid & 63;
    const int l15 = lane & 15, lg = lane >> 4;
    const int wid = tid >> 6;
    const int wr = wid >> 1, wc = wid & 1;
    const int m0 = blockIdx.y * 128, n0 = blockIdx.x * 128;
    const int srow = tid >> 3;                // 0..31
    const int scol = (tid & 7) * 8;           // 0..56

    f32x4 acc[4][4];
    #pragma unroll
    for (int mi = 0; mi < 4; ++mi)
        #pragma unroll
        for (int ni = 0; ni < 4; ++ni)
            acc[mi][ni] = (f32x4){0.f, 0.f, 0.f, 0.f};

    for (int kt = 0; kt < K / 64; ++kt) {
        bf16x8 avals[4], bvals[4];
        #pragma unroll
        for (int i = 0; i < 4; ++i) {
            avals[i] = *(const bf16x8*)(A + (size_t)(m0 + i * 32 + srow) * K + kt * 64 + scol);
            int brow = n0 + i * 32 + srow;
            if (GUARD_N) brow = (brow < N) ? brow : (N - 1);
            bvals[i] = *(const bf16x8*)(Bm + (size_t)brow * K + kt * 64 + scol);
        }
        __syncthreads();   // previous iter's reads complete
        #pragma unroll
        for (int i = 0; i < 4; ++i) {
            *(bf16x8*)&As[(i * 32 + srow) * LDA + scol] = avals[i];
            *(bf16x8*)&Bs[(i * 32 + srow) * LDA + scol] = bvals[i];
        }
        __syncthreads();
        #pragma unroll
        for (int ks = 0; ks < 2; ++ks) {
            bf16x8 af[4], bf[4];
            #pragma unroll
            for (int mi = 0; mi < 4; ++mi)
                af[mi] = *(const bf16x8*)&As[(wr * 64 + mi * 16 + l15) * LDA + ks * 32 + lg * 8];
            #pragma unroll
            for (int ni = 0; ni < 4; ++ni)
                bf[ni] = *(const bf16x8*)&Bs[(wc * 64 + ni * 16 + l15) * LDA + ks * 32 + lg * 8];
            #pragma unroll
            for (int mi = 0; mi < 4; ++mi)
                #pragma unroll
                for (int ni = 0; ni < 4; ++ni)
                    acc[mi][ni] = __builtin_amdgcn_mfma_f32_16x16x32_bf16(
                        af[mi], bf[ni], acc[mi][ni], 0, 0, 0);
        }
    }

    #pragma unroll
    for (int ni = 0; ni < 4; ++ni) {
        int n = n0 + wc * 64 + ni * 16 + l15;
        bool nok = (!GUARD_N) || (n < N);
        float bsum = 0.f;
        if (nok) { bsum = bias0[n]; if (bias1) bsum += bias1[n]; }
        int ns = PERM ? ((n & ~31) | ((n & 15) << 1) | ((n >> 4) & 1)) : n;
        #pragma unroll
        for (int mi = 0; mi < 4; ++mi) {
            int m = m0 + wr * 64 + mi * 16 + lg * 4;
            #pragma unroll
            for (int r = 0; r < 4; ++r) {
                float v = acc[mi][ni][r] + bsum;
                if (nok) {
                    if (OUT_BF16)
                        ((unsigned short*)Cptr)[(size_t)(m + r) * ldC + ns] = f2bf(v);
                    else
                        ((float*)Cptr)[(size_t)(m + r) * ldC + ns] = v;
                }
            }
        }
    }
}

// ---------- persistent LSTM layer ----------
// h LDS addressing: byte(row, bc) = row*512 + (bc ^ ((row&7)<<4))  (T2 swizzle)
__device__ __forceinline__ void lstm_step_body(
    int t, const unsigned short* __restrict__ G, size_t gbase,
    unsigned int* __restrict__ cur, unsigned int* __restrict__ nxt,
    char* __restrict__ smem, char* __restrict__ ldsW,
    const bf16x8* __restrict__ wreg, const unsigned short* __restrict__ wstr,
    float (*__restrict__ cst)[4],
    int w, int l, int l15, int lg, int bc,
    unsigned short* __restrict__ h0out, unsigned short* __restrict__ hlast)
{
    const int hxor = (l15 & 7) << 4;

    // ---- prefetch G(t+1): 16 packed u32, in flight across barriers ----
    const unsigned short* Gn = G + ((size_t)(t + 1) * 512 * 1024) + gbase;
    #pragma unroll
    for (int ty = 0; ty < 4; ++ty)
        #pragma unroll
        for (int r = 0; r < 4; ++r)
            nxt[ty * 4 + r] = *(const unsigned int*)(Gn + ty * 256 + (size_t)r * 1024);

    // ---- stream batch 1: frags f=47..55 ----
    bf16x8 sb[SFRAGS];
    #pragma unroll
    for (int sf = 0; sf < 9; ++sf)
        sb[sf] = *(const bf16x8*)(wstr + sf * 512);

    unsigned short hb16[2][4];
    f32x4 acc[4];

    // ================= cg = 0 =================
    #pragma unroll
    for (int ty = 0; ty < 4; ++ty) acc[ty] = (f32x4){0.f, 0.f, 0.f, 0.f};
    #pragma unroll
    for (int ks = 0; ks < 8; ++ks) {
        bf16x8 a = *(const bf16x8*)(smem + l15 * 512 + ((ks * 64 + lg * 16) ^ hxor));
        #pragma unroll
        for (int ty = 0; ty < 4; ++ty) {
            const int f = ty * 8 + ks;
            bf16x8 b;
            if (f < RFRAGS) b = wreg[f];
            else b = *(const bf16x8*)(ldsW + (w * LFRAGS + (f - RFRAGS)) * 1024 + l * 16);
            acc[ty] = __builtin_amdgcn_mfma_f32_16x16x32_bf16(a, b, acc[ty], 0, 0, 0);
        }
    }

    // ---- stream batch 2: frags f=56..63 (hidden under cg0 epilogue + cg1 start) ----
    #pragma unroll
    for (int sf = 9; sf < SFRAGS; ++sf)
        sb[sf] = *(const bf16x8*)(wstr + sf * 512);

    #pragma unroll
    for (int r = 0; r < 4; ++r) {
        float pre[4];
        #pragma unroll
        for (int ty = 0; ty < 4; ++ty)
            pre[ty] = acc[ty][r] + bf2f((unsigned short)(cur[ty * 4 + r] & 0xffffu));
        float ii = sigm(pre[0]), ff = sigm(pre[1]);
        float gg = ftanh(pre[2]), oo = sigm(pre[3]);
        float cn = ff * cst[0][r] + ii * gg;
        cst[0][r] = cn;
        float hn = oo * ftanh(cn);
        hb16[0][r] = f2bf(hn);
    }

    // ================= cg = 1 =================
    #pragma unroll
    for (int ty = 0; ty < 4; ++ty) acc[ty] = (f32x4){0.f, 0.f, 0.f, 0.f};
    #pragma unroll
    for (int ks = 0; ks < 8; ++ks) {
        bf16x8 a = *(const bf16x8*)(smem + l15 * 512 + ((ks * 64 + lg * 16) ^ hxor));
        #pragma unroll
        for (int ty = 0; ty < 4; ++ty) {
            const int f = 32 + ty * 8 + ks;
            bf16x8 b;
            if (f < 47) b = *(const bf16x8*)(ldsW + (w * LFRAGS + (f - RFRAGS)) * 1024 + l * 16);
            else b = sb[f - 47];
            acc[ty] = __builtin_amdgcn_mfma_f32_16x16x32_bf16(a, b, acc[ty], 0, 0, 0);
        }
    }
    #pragma unroll
    for (int r = 0; r < 4; ++r) {
        float pre[4];
        #pragma unroll
        for (int ty = 0; ty < 4; ++ty)
            pre[ty] = acc[ty][r] + bf2f((unsigned short)(cur[ty * 4 + r] >> 16));
        float ii = sigm(pre[0]), ff = sigm(pre[1]);
        float gg = ftanh(pre[2]), oo = sigm(pre[3]);
        float cn = ff * cst[1][r] + ii * gg;
        cst[1][r] = cn;
        float hn = oo * ftanh(cn);
        hb16[1][r] = f2bf(hn);
    }

    // ---- global h outputs ----
    if (h0out) {
        #pragma unroll
        for (int cg = 0; cg < 2; ++cg)
            #pragma unroll
            for (int r = 0; r < 4; ++r)
                h0out[((size_t)t * 512 + bc * 16 + lg * 4 + r) * 256
                      + w * 32 + cg * 16 + l15] = hb16[cg][r];
    }
    if (hlast && t == 127) {
        #pragma unroll
        for (int cg = 0; cg < 2; ++cg)
            #pragma unroll
            for (int r = 0; r < 4; ++r)
                hlast[(size_t)(bc * 16 + lg * 4 + r) * 256
                      + w * 32 + cg * 16 + l15] = hb16[cg][r];
    }

    // barrier 1: all waves done reading h(t-1). DS-drain only; vmcnt stays open.
    asm volatile("s_waitcnt lgkmcnt(0)" ::: "memory");
    __builtin_amdgcn_s_barrier();

    #pragma unroll
    for (int cg = 0; cg < 2; ++cg)
        #pragma unroll
        for (int r = 0; r < 4; ++r) {
            int row = lg * 4 + r;
            int bcol = (w * 32 + cg * 16 + l15) * 2;
            *(unsigned short*)(smem + row * 512 + (bcol ^ ((row & 7) << 4))) = hb16[cg][r];
        }

    // barrier 2: h(t) visible.
    asm volatile("s_waitcnt lgkmcnt(0)" ::: "memory");
    __builtin_amdgcn_s_barrier();
}

__global__ __launch_bounds__(512, 2) void lstm_persist(
    const unsigned short* __restrict__ G,    // [128][512][1024] bf16, cg-interleaved cols
    const float* __restrict__ Whh,           // [1024][256] f32
    const unsigned short* __restrict__ Wstr, // packed streamed frags
    unsigned short* __restrict__ h0out,      // layer0: [t*512+b][256] bf16, else nullptr
    unsigned short* __restrict__ hlast)      // layer1: [512][256] bf16 at t=127, else nullptr
{
    extern __shared__ char smem[];
    char* ldsW = smem + LDS_HB;

    const int lid = threadIdx.x;
    const int w = lid >> 6;
    const int l = lid & 63;
    const int l15 = l & 15, lg = l >> 4;
    const int bc = blockIdx.x;

    // register frags f < 28
    bf16x8 wreg[RFRAGS];
    #pragma unroll
    for (int f = 0; f < RFRAGS; ++f) {
        const int cg = f >> 5, type = (f >> 3) & 3, ks = f & 7;
        const int grow = type * 256 + w * 32 + cg * 16 + l15;
        const int k0 = ks * 32 + lg * 8;
        const float* src = Whh + (size_t)grow * 256 + k0;
        wreg[f] = pack8(*(const float4*)src, *(const float4*)(src + 4));
    }
    // LDS frags f in [28,47)
    for (int f = RFRAGS; f < RFRAGS + LFRAGS; ++f) {
        const int cg = f >> 5, type = (f >> 3) & 3, ks = f & 7;
        const int grow = type * 256 + w * 32 + cg * 16 + l15;
        const int k0 = ks * 32 + lg * 8;
        const float* src = Whh + (size_t)grow * 256 + k0;
        *(bf16x8*)(ldsW + (size_t)(w * LFRAGS + (f - RFRAGS)) * 1024 + l * 16) =
            pack8(*(const float4*)src, *(const float4*)(src + 4));
    }

    for (int i = lid; i < 2048; i += 512) ((unsigned int*)smem)[i] = 0;
    __syncthreads();

    float cst[2][4] = {};
    unsigned int gvA[16], gvB[16];

    const size_t gbase = (size_t)bc * 16 * 1024 + (size_t)lg * 4 * 1024
                       + w * 32 + l15 * 2;
    const unsigned short* wstr = Wstr + (size_t)w * SFRAGS * 512 + l * 8;

    {   // prologue: load t=0 gate values
        const unsigned short* G0 = G + gbase;
        #pragma unroll
        for (int ty = 0; ty < 4; ++ty)
            #pragma unroll
            for (int r = 0; r < 4; ++r)
                gvA[ty * 4 + r] = *(const unsigned int*)(G0 + ty * 256 + (size_t)r * 1024);
    }

    for (int t = 0; t < 128; t += 2) {
        lstm_step_body(t,     G, gbase, gvA, gvB, smem, ldsW, wreg, wstr, cst,
                       w, l, l15, lg, bc, h0out, hlast);
        lstm_step_body(t + 1, G, gbase, gvB, gvA, smem, ldsW, wreg, wstr, cst,
                       w, l, l15, lg, bc, h0out, hlast);
    }
}

// ---------- row softmax over 50257 ----------
__global__ __launch_bounds__(256) void softmax_rows(
    const float* __restrict__ logits, float* __restrict__ out)
{
    const int b = blockIdx.x;
    const int lid = threadIdx.x;
    const float* row = logits + (size_t)b * 50257;
    __shared__ float red[256];

    float m = -3.4e38f;
    for (int v = lid; v < 50257; v += 256) m = fmaxf(m, row[v]);
    red[lid] = m; __syncthreads();
    for (int s = 128; s > 0; s >>= 1) {
        if (lid < s) red[lid] = fmaxf(red[lid], red[lid + s]);
        __syncthreads();
    }
    m = red[0]; __syncthreads();

    float sum = 0.f;
    for (int v = lid; v < 50257; v += 256) sum += __expf(row[v] - m);
    red[lid] = sum; __syncthreads();
    for (int s = 128; s > 0; s >>= 1) {
        if (lid < s) red[lid] += red[lid + s];
        __syncthreads();
    }
    float inv = 1.0f / red[0];

    float* orow = out + (size_t)b * 50257;
    for (int v = lid; v < 50257; v += 256) orow[v] = __expf(row[v] - m) * inv;
}

// ---------- host ----------
extern "C" void kernel_launch(void* const* d_in, const int* in_sizes, int n_in,
                              void* d_out, int out_size, void* d_ws, size_t ws_size,
                              hipStream_t stream) {
    (void)in_sizes; (void)n_in; (void)out_size; (void)ws_size;
    const float* x    = (const float*)d_in[0];
    const float* Wih0 = (const float*)d_in[1];
    const float* Whh0 = (const float*)d_in[2];
    const float* bih0 = (const float*)d_in[3];
    const float* bhh0 = (const float*)d_in[4];
    const float* Wih1 = (const float*)d_in[5];
    const float* Whh1 = (const float*)d_in[6];
    const float* bih1 = (const float*)d_in[7];
    const float* bhh1 = (const float*)d_in[8];
    const float* fcW  = (const float*)d_in[9];
    const float* fcb  = (const float*)d_in[10];
    float* out = (float*)d_out;

    char* ws = (char*)d_ws;
    unsigned short* G      = (unsigned short*)ws;                 // 134,217,728 B
    unsigned short* h0all  = (unsigned short*)(ws + 134217728);   // 33,554,432 B
    unsigned short* xb     = h0all;                               // alias: dead before lstm0 writes h0all
    char* misc             = ws + 167772160;
    unsigned short* W0b    = (unsigned short*)(misc);             // 262,144 B
    unsigned short* W1b    = (unsigned short*)(misc + 262144);    // 524,288 B
    unsigned short* hlastb = (unsigned short*)(misc + 786432);    // 262,144 B
    unsigned short* Wstr0  = (unsigned short*)(misc + 1048576);   // 139,264 B
    unsigned short* Wstr1  = (unsigned short*)(misc + 1187840);   // 139,264 B
    float* logits          = (float*)ws;                          // reuses G region
    unsigned short* fcWb   = (unsigned short*)(ws + 103809024);   // in G region, past logits

    static bool attr_set = false;
    if (!attr_set) {
        hipFuncSetAttribute((const void*)lstm_persist,
                            hipFuncAttributeMaxDynamicSharedMemorySize, LDS_TOTAL);
        attr_set = true;
    }

    // ----- layer 0 -----
    cvt_x_transpose<<<4096, 256, 0, stream>>>(x, xb);
    cvt_f32_bf16<<<64, 256, 0, stream>>>(Wih0, W0b, 16384);
    pack_stream<<<34, 256, 0, stream>>>(Whh0, Wstr0);
    gemm_mfma<128, true, false, true><<<dim3(8, 512), 256, 0, stream>>>(
        xb, W0b, bih0, bhh0, G, 1024, 1024);
    lstm_persist<<<32, 512, LDS_TOTAL, stream>>>(G, Whh0, Wstr0, h0all, nullptr);
    // ----- layer 1 -----
    cvt_f32_bf16<<<128, 256, 0, stream>>>(Wih1, W1b, 32768);
    pack_stream<<<34, 256, 0, stream>>>(Whh1, Wstr1);
    gemm_mfma<256, true, false, true><<<dim3(8, 512), 256, 0, stream>>>(
        h0all, W1b, bih1, bhh1, G, 1024, 1024);
    lstm_persist<<<32, 512, LDS_TOTAL, stream>>>(G, Whh1, Wstr1, nullptr, hlastb);
    // ----- FC + softmax -----
    cvt_f32_bf16<<<6283, 256, 0, stream>>>(fcW, fcWb, 1608224);
    gemm_mfma<256, false, true, false><<<dim3(393, 4), 256, 0, stream>>>(
        hlastb, fcWb, fcb, nullptr, logits, 50257, 50257);
    softmax_rows<<<512, 256, 0, stream>>>(logits, out);
}